// Round 1
// baseline (2312.304 us; speedup 1.0000x reference)
//
#include <hip/hip_runtime.h>
#include <cstdint>

#define BB 2048
#define TT 200
#define DD 128
#define H1 128
#define H2 64
#define MASK_PAD -4294967295.0f

// ---------------------------------------------------------------------------
// Fold kernel: precompute
//   WkF [d][h] = W0[128+d][h] - W0[256+d][h]   (k coefficient after concat fold)
//   WqkF[d][h] = W0[384+d][h]                  (q*k coefficient)
//   W1t [g][h] = W1[h][g]                      (transposed for contiguous s_load)
// into d_ws (floats): WkF @0, WqkF @16384, W1t @32768  (total 40960 floats)
// ---------------------------------------------------------------------------
__global__ void din_fold(const float* __restrict__ W0,
                         const float* __restrict__ W1,
                         float* __restrict__ ws) {
  int i = blockIdx.x * blockDim.x + threadIdx.x;
  float* WkF  = ws;
  float* WqkF = ws + 16384;
  float* W1t  = ws + 32768;
  if (i < 16384) {
    int d = i >> 7, h = i & 127;
    WkF[i]  = W0[(128 + d) * 128 + h] - W0[(256 + d) * 128 + h];
    WqkF[i] = W0[(384 + d) * 128 + h];
  } else if (i < 24576) {
    int j = i - 16384;
    int g = j >> 7, h = j & 127;
    W1t[j] = W1[h * 64 + g];
  }
}

// ---------------------------------------------------------------------------
// Main kernel: one block per batch element b. 256 threads.
// Phase 1: qA[h] = b0[h] + sum_d q[d]*(W0a+W0c)[d][h]        (128 threads)
// Phase 2: thread t (t<200) computes its logit:
//          h0 = prelu(qA + k@WkF + (q*k)@WqkF, a0[t])         (h0 in 128 VGPRs)
//          logit = bout + sum_g prelu(h0@W1t[g] + b1[g], a1[t][g]) * Wout[g]
// Phase 3: masked softmax over t via LDS broadcast reduces.
// Phase 4: out[b][d] = sum_t attn[t] * val[b][t][d]  (float4, 8-way t split)
// ---------------------------------------------------------------------------
__global__ __launch_bounds__(256) void din_main(
    const float* __restrict__ query, const float* __restrict__ key,
    const float* __restrict__ val, const int* __restrict__ mask,
    const float* __restrict__ W0, const float* __restrict__ b0,
    const float* __restrict__ a0, const float* __restrict__ b1,
    const float* __restrict__ a1, const float* __restrict__ Wout,
    const float* __restrict__ bout,
    const float* __restrict__ WkF, const float* __restrict__ WqkF,
    const float* __restrict__ W1t,
    float* __restrict__ out) {
  const int b = blockIdx.x;
  const int tid = threadIdx.x;

  __shared__ float qs[DD];       // query row
  __shared__ float qas[H1];      // qA + b0
  __shared__ float eLDS[256];    // logits, then exp weights
  __shared__ float red[1024];    // PV partial sums (8 groups x 128 d)

  // ---- stage q ----
  if (tid < DD) qs[tid] = query[(size_t)b * DD + tid];
  __syncthreads();

  // ---- phase 1: qA ----
  if (tid < H1) {
    float acc = b0[tid];
    #pragma unroll 4
    for (int d = 0; d < DD; ++d) {
      acc += qs[d] * (W0[d * H1 + tid] + W0[(256 + d) * H1 + tid]);
    }
    qas[tid] = acc;
  }
  __syncthreads();

  // ---- phase 2: per-thread logit ----
  const int t = tid;
  float logit = 0.0f;
  if (t < TT) {
    float h0[H1];
    #pragma unroll
    for (int h = 0; h < H1; ++h) h0[h] = qas[h];

    const float* krow = key + ((size_t)b * TT + t) * DD;
    #pragma unroll 1
    for (int d0 = 0; d0 < DD; d0 += 4) {
      float4 kv = *(const float4*)(krow + d0);
      float q0 = qs[d0], q1 = qs[d0 + 1], q2 = qs[d0 + 2], q3 = qs[d0 + 3];
      float p0 = q0 * kv.x, p1 = q1 * kv.y, p2 = q2 * kv.z, p3 = q3 * kv.w;
      const float* wk = WkF + d0 * H1;
      const float* wq = WqkF + d0 * H1;
      #pragma unroll
      for (int h = 0; h < H1; ++h) {
        float s = h0[h];
        s += kv.x * wk[h];
        s += kv.y * wk[H1 + h];
        s += kv.z * wk[2 * H1 + h];
        s += kv.w * wk[3 * H1 + h];
        s += p0 * wq[h];
        s += p1 * wq[H1 + h];
        s += p2 * wq[2 * H1 + h];
        s += p3 * wq[3 * H1 + h];
        h0[h] = s;
      }
    }

    // prelu layer 0
    const float* a0row = a0 + (size_t)t * H1;
    #pragma unroll
    for (int h = 0; h < H1; ++h) {
      float a = a0row[h];
      float v = h0[h];
      h0[h] = v > 0.0f ? v : a * v;
    }

    // layer 1 fused with layer 2
    float lg = bout[0];
    const float* a1row = a1 + (size_t)t * H2;
    #pragma unroll 1
    for (int g = 0; g < H2; ++g) {
      const float* w1 = W1t + g * H1;
      float acc0 = 0.0f, acc1 = 0.0f, acc2 = 0.0f, acc3 = 0.0f;
      #pragma unroll
      for (int h = 0; h < H1; h += 4) {
        acc0 += h0[h]     * w1[h];
        acc1 += h0[h + 1] * w1[h + 1];
        acc2 += h0[h + 2] * w1[h + 2];
        acc3 += h0[h + 3] * w1[h + 3];
      }
      float acc = ((acc0 + acc1) + (acc2 + acc3)) + b1[g];
      float a = a1row[g];
      acc = acc > 0.0f ? acc : a * acc;
      lg += acc * Wout[g];
    }

    int m = mask[(size_t)b * TT + t];
    logit = (m == 0) ? MASK_PAD : lg;
  }

  // ---- phase 3: softmax over t ----
  eLDS[tid] = (t < TT) ? logit : -INFINITY;
  __syncthreads();
  float mx = -INFINITY;
  for (int i = 0; i < TT; ++i) mx = fmaxf(mx, eLDS[i]);
  __syncthreads();  // done reading logits before overwrite
  float e = 0.0f;
  if (t < TT) e = __expf(logit - mx);
  eLDS[tid] = e;
  __syncthreads();
  float denom = 0.0f;
  for (int i = 0; i < TT; ++i) denom += eLDS[i];
  float inv = 1.0f / denom;

  // ---- phase 4: PV (attn-weighted sum of val) ----
  const int group = tid >> 5;          // 0..7, owns 25 t's
  const int d4 = (tid & 31) * 4;       // float4 column
  const float* vb = val + (size_t)b * TT * DD;
  float4 acc4 = make_float4(0.f, 0.f, 0.f, 0.f);
  #pragma unroll 1
  for (int ttc = group * 25; ttc < group * 25 + 25; ++ttc) {
    float4 v = *(const float4*)(vb + (size_t)ttc * DD + d4);
    float w = eLDS[ttc];
    acc4.x += w * v.x;
    acc4.y += w * v.y;
    acc4.z += w * v.z;
    acc4.w += w * v.w;
  }
  *(float4*)&red[group * DD + d4] = acc4;
  __syncthreads();
  if (tid < DD) {
    float s = 0.0f;
    #pragma unroll
    for (int g = 0; g < 8; ++g) s += red[g * DD + tid];
    out[(size_t)b * DD + tid] = s * inv;
  }
}

extern "C" void kernel_launch(void* const* d_in, const int* in_sizes, int n_in,
                              void* d_out, int out_size, void* d_ws, size_t ws_size,
                              hipStream_t stream) {
  const float* query = (const float*)d_in[0];
  const float* key   = (const float*)d_in[1];
  const float* val   = (const float*)d_in[2];
  const int*   mask  = (const int*)d_in[3];
  const float* W0    = (const float*)d_in[4];
  const float* b0    = (const float*)d_in[5];
  const float* a0    = (const float*)d_in[6];
  const float* W1    = (const float*)d_in[7];
  const float* b1    = (const float*)d_in[8];
  const float* a1    = (const float*)d_in[9];
  const float* Wout  = (const float*)d_in[10];
  const float* bout  = (const float*)d_in[11];
  float* out = (float*)d_out;
  float* ws  = (float*)d_ws;

  hipLaunchKernelGGL(din_fold, dim3(96), dim3(256), 0, stream, W0, W1, ws);
  hipLaunchKernelGGL(din_main, dim3(BB), dim3(256), 0, stream,
                     query, key, val, mask, W0, b0, a0, b1, a1, Wout, bout,
                     ws, ws + 16384, ws + 32768, out);
}

// Round 2
// 255.971 us; speedup vs baseline: 9.0335x; 9.0335x over previous
//
#include <hip/hip_runtime.h>
#include <cstdint>

#define BB 2048
#define TT 200
#define DD 128
#define H1 128
#define H2 64
#define MASK_PAD -4294967295.0f

typedef __attribute__((ext_vector_type(8))) short short8;
typedef __attribute__((ext_vector_type(4))) float floatx4;

static __device__ __forceinline__ unsigned short f2bf(float x) {
  union { float f; unsigned int u; } v; v.f = x;
  unsigned int r = v.u + 0x7FFF + ((v.u >> 16) & 1);  // RNE
  return (unsigned short)(r >> 16);
}

// ---------------------------------------------------------------------------
// Fold kernel -> ws (bf16):
//   Wcat_T[h][k] (128 x 256): k<128 -> (W0b - W0c)^T   (k coefficient)
//                              k>=128 -> (W0d)^T        (q*k coefficient)
//   W1t  [g][h] (64 x 128):   W1^T
// ws bytes: Wcat @0 (65536 B), W1t @65536 (16384 B)
// ---------------------------------------------------------------------------
__global__ void din_fold(const float* __restrict__ W0,
                         const float* __restrict__ W1,
                         unsigned short* __restrict__ ws) {
  int i = blockIdx.x * blockDim.x + threadIdx.x;
  if (i < 32768) {
    int h = i >> 8, k = i & 255;
    float v;
    if (k < 128) v = W0[(128 + k) * 128 + h] - W0[(256 + k) * 128 + h];
    else         v = W0[(384 + (k - 128)) * 128 + h];
    ws[i] = f2bf(v);
  } else if (i < 40960) {
    int j = i - 32768;
    int g = j >> 7, hh = j & 127;
    ws[32768 + j] = f2bf(W1[hh * 64 + g]);
  }
}

// ---------------------------------------------------------------------------
// Main kernel: one block per b, 256 threads (4 waves).
// Streams 13 M-tiles of 16 rows: stage(bf16,swizzled) -> GEMM1(mfma) ->
// prelu -> GEMM2(mfma) -> prelu -> logit reduce. Then softmax + PV.
// ---------------------------------------------------------------------------
__global__ __launch_bounds__(256, 2) void din_main(
    const float* __restrict__ query, const float* __restrict__ key,
    const float* __restrict__ val, const int* __restrict__ mask,
    const float* __restrict__ W0, const float* __restrict__ b0,
    const float* __restrict__ a0, const float* __restrict__ b1,
    const float* __restrict__ a1, const float* __restrict__ Wout,
    const float* __restrict__ bout,
    const unsigned short* __restrict__ wsb,   // bf16 weights
    float* __restrict__ out) {
  const int b = blockIdx.x;
  const int tid = threadIdx.x;
  const int w = tid >> 6;      // wave 0..3
  const int l = tid & 63;      // lane

  __shared__ unsigned short Atile[16 * 256];  // 8 KB  (k | q*k) bf16, swizzled
  __shared__ unsigned short A2t[16 * 128];    // 4 KB  post-prelu H0, swizzled
  __shared__ float qs[DD];
  __shared__ float qas[H1];
  __shared__ float logitsAll[208];
  __shared__ float eLDS[256];
  __shared__ float partial[4][16];
  __shared__ float red4[8];
  __shared__ float red[8 * DD];               // 4 KB PV partials

  const unsigned short* Wcat = wsb;           // [128][256]
  const unsigned short* W1t  = wsb + 32768;   // [64][128]

  // ---- stage q ----
  if (tid < DD) qs[tid] = query[(size_t)b * DD + tid];
  __syncthreads();

  // ---- preload B fragments into registers (per wave) ----
  // GEMM1: wave w owns n-tiles {2w, 2w+1}; frag lane: col=(l&15), k=(l>>4)*8+e
  short8 B1f[2][8];
  #pragma unroll
  for (int ntl = 0; ntl < 2; ++ntl) {
    int hrow = (2 * w + ntl) * 16 + (l & 15);
    #pragma unroll
    for (int ks = 0; ks < 8; ++ks) {
      B1f[ntl][ks] = *(const short8*)(Wcat + hrow * 256 + ks * 32 + (l >> 4) * 8);
    }
  }
  // GEMM2: wave w owns n-tile w (cols g = w*16 + (l&15)), K=128 -> 4 ksteps
  short8 B2f[4];
  {
    int grow = w * 16 + (l & 15);
    #pragma unroll
    for (int ks = 0; ks < 4; ++ks) {
      B2f[ks] = *(const short8*)(W1t + grow * 128 + ks * 32 + (l >> 4) * 8);
    }
  }

  // ---- qA[h] = b0[h] + sum_d q[d]*(W0a+W0c)[d][h]  (fp32, threads 0..127) ----
  if (tid < H1) {
    float acc = b0[tid];
    #pragma unroll 4
    for (int d = 0; d < DD; ++d) {
      acc += qs[d] * (W0[d * H1 + tid] + W0[(256 + d) * H1 + tid]);
    }
    qas[tid] = acc;
  }

  // per-lane constants for epilogue 2
  const int gcol = w * 16 + (l & 15);
  const float b1v = b1[gcol];
  const float wov = Wout[gcol];

  __syncthreads();

  // =================== M-tile loop ===================
  for (int mt = 0; mt < 13; ++mt) {
    // ---- stage 16 rows of A = [k | q*k] as bf16, XOR-swizzled ----
    #pragma unroll
    for (int i = 0; i < 2; ++i) {
      int f = tid + 256 * i;          // 0..511 float4s
      int t_loc = f >> 5;             // row 0..15
      int d4 = (f & 31) * 4;          // col (floats)
      int t_glob = mt * 16 + t_loc;
      if (t_glob < TT) {
        float4 kv = *(const float4*)(key + ((size_t)b * TT + t_glob) * DD + d4);
        float4 qv = *(const float4*)(qs + d4);
        ushort4 ku, qku;
        ku.x = f2bf(kv.x); ku.y = f2bf(kv.y); ku.z = f2bf(kv.z); ku.w = f2bf(kv.w);
        qku.x = f2bf(qv.x * kv.x); qku.y = f2bf(qv.y * kv.y);
        qku.z = f2bf(qv.z * kv.z); qku.w = f2bf(qv.w * kv.w);
        int swz = (t_loc & 7) << 4;
        char* base = (char*)Atile + t_loc * 512;
        *(ushort4*)(base + ((d4 * 2) ^ swz)) = ku;
        *(ushort4*)(base + ((256 + d4 * 2) ^ swz)) = qku;
      }
    }
    __syncthreads();  // S1

    // ---- GEMM1: acc[ntl] = A(16x256) @ Wcat-cols ----
    floatx4 acc[2];
    acc[0] = (floatx4)(0.0f); acc[1] = (floatx4)(0.0f);
    {
      int row = l & 15;
      int swz = (row & 7) << 4;
      const char* abase = (const char*)Atile + row * 512;
      #pragma unroll
      for (int ks = 0; ks < 8; ++ks) {
        short8 af = *(const short8*)(abase + ((ks * 64 + (l >> 4) * 16) ^ swz));
        acc[0] = __builtin_amdgcn_mfma_f32_16x16x32_bf16(af, B1f[0][ks], acc[0], 0, 0, 0);
        acc[1] = __builtin_amdgcn_mfma_f32_16x16x32_bf16(af, B1f[1][ks], acc[1], 0, 0, 0);
      }
    }
    // ---- epilogue 1: +qA, PReLU(a0), write A2 (bf16, swizzled) ----
    #pragma unroll
    for (int ntl = 0; ntl < 2; ++ntl) {
      int h = (2 * w + ntl) * 16 + (l & 15);
      float qa = qas[h];
      #pragma unroll
      for (int r = 0; r < 4; ++r) {
        int t_loc = (l >> 4) * 4 + r;
        int t_glob = mt * 16 + t_loc;
        float v = acc[ntl][r] + qa;
        float a = (t_glob < TT) ? a0[t_glob * H1 + h] : 0.0f;
        v = v > 0.0f ? v : a * v;
        int byte = t_loc * 256 + ((h * 2) ^ ((t_loc & 7) << 4));
        *(unsigned short*)((char*)A2t + byte) = f2bf(v);
      }
    }
    __syncthreads();  // S2

    // ---- GEMM2: acc2 = A2(16x128) @ W1t-cols ----
    floatx4 acc2 = (floatx4)(0.0f);
    {
      int row = l & 15;
      int swz = (row & 7) << 4;
      const char* abase = (const char*)A2t + row * 256;
      #pragma unroll
      for (int ks = 0; ks < 4; ++ks) {
        short8 af = *(const short8*)(abase + ((ks * 64 + (l >> 4) * 16) ^ swz));
        acc2 = __builtin_amdgcn_mfma_f32_16x16x32_bf16(af, B2f[ks], acc2, 0, 0, 0);
      }
    }
    // ---- epilogue 2: +b1, PReLU(a1), *Wout, reduce over g ----
    {
      float p[4];
      #pragma unroll
      for (int r = 0; r < 4; ++r) {
        int t_loc = (l >> 4) * 4 + r;
        int t_glob = mt * 16 + t_loc;
        float x = acc2[r] + b1v;
        float a = (t_glob < TT) ? a1[t_glob * H2 + gcol] : 0.0f;
        x = x > 0.0f ? x : a * x;
        p[r] = x * wov;
      }
      #pragma unroll
      for (int m = 1; m < 16; m <<= 1) {
        #pragma unroll
        for (int r = 0; r < 4; ++r) p[r] += __shfl_xor(p[r], m);
      }
      if ((l & 15) == 0) {
        #pragma unroll
        for (int r = 0; r < 4; ++r) partial[w][(l >> 4) * 4 + r] = p[r];
      }
    }
    __syncthreads();  // S3

    // ---- combine partials -> logits ----
    if (tid < 16) {
      int t_glob = mt * 16 + tid;
      if (t_glob < TT) {
        float lg = bout[0] + partial[0][tid] + partial[1][tid] +
                   partial[2][tid] + partial[3][tid];
        int m = mask[(size_t)b * TT + t_glob];
        logitsAll[t_glob] = (m == 0) ? MASK_PAD : lg;
      }
    }
    // next stage's A-tile writes are safe: all waves passed S3
  }
  __syncthreads();

  // =================== softmax over t ===================
  float lv = (tid < TT) ? logitsAll[tid] : -INFINITY;
  {
    float m = lv;
    #pragma unroll
    for (int off = 32; off >= 1; off >>= 1) m = fmaxf(m, __shfl_xor(m, off));
    if (l == 0) red4[w] = m;
  }
  __syncthreads();
  float mx = fmaxf(fmaxf(red4[0], red4[1]), fmaxf(red4[2], red4[3]));
  float e = (tid < TT) ? __expf(lv - mx) : 0.0f;
  eLDS[tid] = e;
  {
    float s = e;
    #pragma unroll
    for (int off = 32; off >= 1; off >>= 1) s += __shfl_xor(s, off);
    if (l == 0) red4[4 + w] = s;
  }
  __syncthreads();
  float denom = red4[4] + red4[5] + red4[6] + red4[7];
  float inv = 1.0f / denom;

  // =================== PV: out[b][d] = sum_t attn[t]*val[b][t][d] ============
  const int group = tid >> 5;       // 0..7, each owns 25 t's
  const int d4 = (tid & 31) * 4;
  const float* vb = val + (size_t)b * TT * DD;
  float4 acc4 = make_float4(0.f, 0.f, 0.f, 0.f);
  #pragma unroll 1
  for (int t = group * 25; t < group * 25 + 25; ++t) {
    float4 v = *(const float4*)(vb + (size_t)t * DD + d4);
    float wt = eLDS[t];
    acc4.x += wt * v.x; acc4.y += wt * v.y;
    acc4.z += wt * v.z; acc4.w += wt * v.w;
  }
  *(float4*)&red[group * DD + d4] = acc4;
  __syncthreads();
  if (tid < DD) {
    float s = 0.0f;
    #pragma unroll
    for (int g = 0; g < 8; ++g) s += red[g * DD + tid];
    out[(size_t)b * DD + tid] = s * inv;
  }
}

extern "C" void kernel_launch(void* const* d_in, const int* in_sizes, int n_in,
                              void* d_out, int out_size, void* d_ws, size_t ws_size,
                              hipStream_t stream) {
  const float* query = (const float*)d_in[0];
  const float* key   = (const float*)d_in[1];
  const float* val   = (const float*)d_in[2];
  const int*   mask  = (const int*)d_in[3];
  const float* W0    = (const float*)d_in[4];
  const float* b0    = (const float*)d_in[5];
  const float* a0    = (const float*)d_in[6];
  const float* W1    = (const float*)d_in[7];
  const float* b1    = (const float*)d_in[8];
  const float* a1    = (const float*)d_in[9];
  const float* Wout  = (const float*)d_in[10];
  const float* bout  = (const float*)d_in[11];
  float* out = (float*)d_out;
  unsigned short* ws = (unsigned short*)d_ws;

  hipLaunchKernelGGL(din_fold, dim3(160), dim3(256), 0, stream, W0, W1, ws);
  hipLaunchKernelGGL(din_main, dim3(BB), dim3(256), 0, stream,
                     query, key, val, mask, W0, b0, a0, b1, a1, Wout, bout,
                     ws, out);
}